// Round 2
// 283.235 us; speedup vs baseline: 1.0441x; 1.0441x over previous
//
#include <hip/hip_runtime.h>

#define PS 7
#define NP 10
#define WIN 20
#define STR 4
#define LL 14          // WIN - PS + 1
#define HALF 7
#define HH 160
#define WW 160
#define BCN 32         // B*C
#define NX 36          // positions per axis
#define PPOS 1296      // NX*NX
#define EMBD 128
#define NTASK (BCN * PPOS * NP)   // 414720
#define NEV (PPOS * NP)           // 12960 events per plane
#define CAP 512                   // per-tile event list capacity (8x8 tiles)
#define NTILE 400                 // 20x20 tiles of 8x8 per plane

// ---------------- phase 0: M = Wp@Wb, K[n] = (bp+pos_emb[n])@Wb + bb ---------
// Extended: also builds the 16x16 u64 lane-mask table MT. MT[(ey+7)*16+(ex+7)]
// has bit (r8*8+c8) set iff tile-pixel (r8,c8) lies in the 7x7 patch whose
// top-left is at tile-relative offset (ey,ex). Borders (clamped idx 0/15) are
// all-zero, so out-of-range offsets give empty masks (subsumes ih/ch flags).
__global__ __launch_bounds__(256) void k_mk(const float* __restrict__ Wp,
                                            const float* __restrict__ bp,
                                            const float* __restrict__ pe,
                                            const float* __restrict__ Wb,
                                            const float* __restrict__ bb,
                                            float* __restrict__ M,
                                            float* __restrict__ K,
                                            unsigned long long* __restrict__ MT) {
    int t = blockIdx.x * 256 + threadIdx.x;
    if (t < 49 * 49) {
        int k = t / 49, d = t % 49;
        float acc = 0.f;
        for (int e = 0; e < EMBD; ++e) acc += Wp[k * EMBD + e] * Wb[e * 49 + d];
        M[t] = acc;
    } else if (t < 49 * 49 + NP * 49) {
        int u = t - 49 * 49;
        int n = u / 49, d = u % 49;
        float acc = bb[d];
        for (int e = 0; e < EMBD; ++e) acc += (bp[e] + pe[n * EMBD + e]) * Wb[e * 49 + d];
        K[u] = acc;
    } else if (t < 49 * 49 + NP * 49 + 256) {
        int u = t - (49 * 49 + NP * 49);
        int ey = (u >> 4) - 7, ex = (u & 15) - 7;
        int r0 = ey > 0 ? ey : 0, r1 = ey + 6 < 7 ? ey + 6 : 7;
        int c0 = ex > 0 ? ex : 0, c1 = ex + 6 < 7 ? ex + 6 : 7;
        unsigned long long m = 0ull;
        if (r0 <= r1 && c0 <= c1) {
            unsigned colp = ((1u << (c1 - c0 + 1)) - 1u) << c0;
            for (int rr = r0; rr <= r1; ++rr)
                m |= (unsigned long long)colp << (8 * rr);
        }
        MT[u] = m;
    }
}

// ---------------- phase 1: sim + top-10 + FUSED den (round-16 proven body) ---
// 4 independent waves per block (no LDS, no barriers). CRITICAL (round-18
// lesson): wv must go through readfirstlane so pos/x/y/plane stay in SGPRs —
// deriving them from tid>>6 directly made the whole body compiler-divergent
// (SGPR 80->32, the 490 s_load taps became vector loads, 2x regression).
// This round: den FMA chain split into 4 independent accumulators (the old
// single chain was 49 dependent FMAs ~196cy at ~4 waves/SIMD).
__global__ __launch_bounds__(256) void k_sim(const float* __restrict__ img,
                                             const float* __restrict__ Mg,
                                             const float* __restrict__ Kg,
                                             unsigned* __restrict__ xy,
                                             float* __restrict__ pd) {
    int tid  = threadIdx.x;
    int wv   = __builtin_amdgcn_readfirstlane(tid >> 6);   // SGPR wave id
    int lane = tid & 63;
    int gt   = blockIdx.x * 4 + wv;    // SALU
    int pos  = gt % PPOS;
    int bc   = gt / PPOS;
    int ix = pos / NX, iy = pos % NX;
    int x = ix * STR, y = iy * STR;
    int xb0 = max(x - HALF, 0), yb0 = max(y - HALF, 0);
    int jmax = x + 6 - xb0;   // valid j <= jmax
    int imax = y + 6 - yb0;   // <= 13 always
    const float* plane = img + bc * (HH * WW);   // SGPR base

    // ref patch 7x7, wave-uniform -> s_loads
    float rf[49];
#pragma unroll
    for (int a = 0; a < PS; ++a)
#pragma unroll
        for (int b = 0; b < PS; ++b)
            rf[a * 7 + b] = plane[(y + a) * WW + (x + b)];

    int B = lane;                      // quad block id, valid < 56
    bool bval = B < 56;
    int gr = B / 14, c = B % 14;       // row-group, col
    int r0 = gr * 4;
    float acc[4] = {0.f, 0.f, 0.f, 0.f};
    const float* wb = plane + yb0 * WW + xb0 + c;
#pragma unroll
    for (int a = 0; a < 10; ++a) {
        int ra = min(r0 + a, 19);      // clamp keeps loads in-window
        const float* rp = wb + ra * WW;
#pragma unroll
        for (int b = 0; b < 7; ++b) {
            float tap = rp[b];
#pragma unroll
            for (int k = 0; k < 4; ++k) {
                int ai = a - k;
                if (ai >= 0 && ai < 7) acc[k] += tap * rf[ai * 7 + b];
            }
        }
    }
    float v[4]; int vidx[4];
#pragma unroll
    for (int k = 0; k < 4; ++k) {
        int rr = r0 + k;
        bool ok = bval && (rr <= imax) && (c <= jmax);  // imax<=13 masks rows 14/15
        v[k] = ok ? acc[k] : -INFINITY;
        vidx[k] = rr * 14 + c;         // monotone in lane per slot
    }

    // M column d cached per lane (rf[] live range ends above -> regs reused)
    int ld = min(lane, 48);
    float Mc[49];
#pragma unroll
    for (int j = 0; j < 49; ++j) Mc[j] = Mg[j * 49 + ld];  // coalesced, L1-hot

    bool act = lane < 49;
    int tbase = (bc * PPOS + pos) * NP;

    for (int n = 0; n < NP; ++n) {
        float bv = fmaxf(fmaxf(v[0], v[1]), fmaxf(v[2], v[3]));
#pragma unroll
        for (int off = 32; off >= 1; off >>= 1)
            bv = fmaxf(bv, __shfl_xor(bv, off));
        unsigned long long ms[4];
        ms[0] = __ballot(v[0] == bv);
        ms[1] = __ballot(v[1] == bv);
        ms[2] = __ballot(v[2] == bv);
        ms[3] = __ballot(v[3] == bv);
        int best = 1 << 30, slotw = 0, lanew = 0;
#pragma unroll
        for (int s = 0; s < 4; ++s) {
            if (ms[s]) {
                int l  = __ffsll(ms[s]) - 1;                       // SGPR
                int id = __builtin_amdgcn_readlane(vidx[s], l);    // SGPR
                if (id < best) { best = id; slotw = s; lanew = l; }
            }
        }
        int bi = best;                       // SGPR raster idx (unique)
#pragma unroll
        for (int s = 0; s < 4; ++s)
            if (s == slotw && lane == lanew) v[s] = -INFINITY;

        int oy = bi / 14, ox = bi % 14;      // SALU
        int x_i = oy + xb0;        // source bug kept: col start = row off + xb0
        int y_i = ox + yb0;        // row start = col off + yb0
        int t = tbase + n;
        if (lane == 0) xy[t] = (unsigned)x_i | ((unsigned)y_i << 8);
        const float* src = plane + (yb0 + oy) * WW + (xb0 + ox);   // SGPR base
        // den[lane] = K[n][lane] + sum_j patch_j * Mc[j];
        // patch_j = src[(j%7)*WW + j/7]  (transposed patch, uniform -> s_load)
        // 4 independent FMA chains (dep 196cy -> ~52cy), summed pairwise.
        float d0 = Kg[n * 49 + ld], d1 = 0.f, d2 = 0.f, d3 = 0.f;
#pragma unroll
        for (int j = 0; j < 48; j += 4) {
            d0 = fmaf(src[((j + 0) % 7) * WW + ((j + 0) / 7)], Mc[j + 0], d0);
            d1 = fmaf(src[((j + 1) % 7) * WW + ((j + 1) / 7)], Mc[j + 1], d1);
            d2 = fmaf(src[((j + 2) % 7) * WW + ((j + 2) / 7)], Mc[j + 2], d2);
            d3 = fmaf(src[((j + 3) % 7) * WW + ((j + 3) / 7)], Mc[j + 3], d3);
        }
        d0 = fmaf(src[(48 % 7) * WW + (48 / 7)], Mc[48], d0);
        float den = (d0 + d1) + (d2 + d3);
        if (act) pd[(size_t)t * 49 + lane] = den;
    }
}

// ---------------- phase 3: build (LDS uint2 list) + replay -------------------
// This round: per-entry hit predicates replaced by precomputed 64-bit lane
// masks. Build packs {t} and {hidx, cidx, s8q} into a uint2 entry; apply
// fetches masks from the 2KB MT table via SCALAR loads (uniform indices) and
// applies them with v_cndmask_b32 ..., s[pair] (inline asm). Per-entry VALU
// drops ~19 -> ~12; SALU stays flat (mask indices precomputed at build).
__global__ __launch_bounds__(256) void k_apply(const float* __restrict__ img,
                                               const unsigned* __restrict__ xy,
                                               const float* __restrict__ pd,
                                               const unsigned long long* __restrict__ mt,
                                               float* __restrict__ out) {
    __shared__ uint2 lsts[4][CAP];
    int tid  = threadIdx.x;
    int wv   = tid >> 6;
    int lane = tid & 63;
    int gt   = blockIdx.x * 4 + wv;          // global tile id
    int bc   = gt / NTILE;
    int tile = gt % NTILE;
    int tx0 = (tile % 20) * 8, ty0 = (tile / 20) * 8;
    int tx1 = tx0 + 7, ty1 = ty0 + 7;
    const unsigned* xs = xy + bc * NEV;
    uint2* lst = lsts[wv];

    // ---- build: interval-restricted scan ----
    int a0 = (tx0 <= 19) ? 0 : ((tx0 - 9) >> 2), a1 = min(35, (tx0 + 14) >> 2);
    int b0 = (ty0 <= 19) ? 0 : ((ty0 - 9) >> 2), b1 = min(35, (ty0 + 14) >> 2);
    if (a0 > b0) { int t0 = a0; a0 = b0; b0 = t0; int t1 = a1; a1 = b1; b1 = t1; }
    int lo0 = a0, lo1 = 0, len0, len1;
    if (b0 <= a1 + 1) { len0 = max(a1, b1) - lo0 + 1; len1 = 0; }
    else              { len0 = a1 - a0 + 1; lo1 = b0; len1 = b1 - b0 + 1; }
    int nU = len0 + len1;                    // <= 14
    unsigned m = 65536u / (unsigned)nU + 1u; // exact fastdiv (k < 4681, nU <= 14)
    int npos = nU * nU;

    unsigned cnt = 0;
    for (int base = 0; base < npos; base += 64) {
        int k = base + lane;
        bool valid = k < npos;
        unsigned kk = valid ? (unsigned)k : 0u;
        int ki = (int)((kk * m) >> 16);
        int kj = (int)kk - ki * nU;
        int ixp = (ki < len0) ? (lo0 + ki) : (lo1 + ki - len0);
        int iyp = (kj < len0) ? (lo0 + kj) : (lo1 + kj - len0);
        int pos = ixp * NX + iyp;
        const unsigned* ep = xs + pos * NP;

        unsigned ev[NP];
#pragma unroll
        for (int n = 0; n < NP; ++n) ev[n] = ep[n];

        unsigned rel = 0;
        unsigned w0[NP], w1[NP];
#pragma unroll
        for (int n = 0; n < NP; ++n) {
            unsigned u = ev[n];
            int x_i = (int)(u & 255u);
            int y_i = (int)((u >> 8) & 255u);
            bool ih = (x_i <= tx1) && (x_i + 6 >= tx0) &&
                      (y_i <= ty1) && (y_i + 6 >= ty0);
            bool ch = (x_i <= ty1) && (x_i + 6 >= ty0) &&
                      (y_i <= tx1) && (y_i + 6 >= tx0);
            bool any = valid && (ih || ch);
            rel |= any ? (1u << n) : 0u;
            // tile-relative offsets: image-hit uses (ey=y_i-ty0, ex=x_i-tx0),
            // counter-hit uses transposed (x_i-ty0, y_i-tx0). ih/ch guarantee
            // range [-6,7] -> idx nibble in [1,14]; miss -> idx 0 (zero mask).
            int eyH = y_i - ty0, exH = x_i - tx0;
            int eyC = x_i - ty0, exC = y_i - tx0;
            unsigned hidx = ih ? (unsigned)(((eyH + 7) << 4) | (exH + 7)) : 0u;
            unsigned cidx = ch ? (unsigned)(((eyC + 7) << 4) | (exC + 7)) : 0u;
            unsigned s8q  = ih ? (unsigned)(((7 * eyH + exH) + 48) << 2) : 0u; // <=416, 9b
            w0[n] = (unsigned)(pos * NP + n);
            w1[n] = hidx | (cidx << 8) | (s8q << 16);
        }
        int myc = __popc(rel);
        int scan = myc;
#pragma unroll
        for (int off = 1; off < 64; off <<= 1) {
            int o = __shfl_up(scan, off);
            scan += (lane >= off) ? o : 0;
        }
        int excl  = (int)cnt + scan - myc;
        int total = __shfl(scan, 63);
        int w = excl;
#pragma unroll
        for (int n = 0; n < NP; ++n) {
            if ((rel >> n) & 1u) { if (w < CAP) lst[w] = make_uint2(w0[n], w1[n]); ++w; }
        }
        cnt += (unsigned)total;
    }
    if (cnt > CAP) cnt = CAP;
    unsigned cntp = (cnt + 7u) & ~7u;
    if (cntp > CAP) cntp = CAP;
    if (lane < (int)(cntp - cnt)) lst[cnt + lane] = make_uint2(0u, 0u); // pad: zero masks
    int cntN = (int)cntp;

    // ---- apply: batch-of-8, scalar mask lookup, cndmask with SGPR-pair ----
    int r8 = lane >> 3, c8 = lane & 7;
    int r  = ty0 + r8;
    int cc = tx0 + c8;
    float im = img[bc * (HH * WW) + r * WW + cc];
    float c  = 1.0f;
    const float* ds = pd + (size_t)bc * ((size_t)NEV * 49);
    int vOff2 = (r8 * 7 + c8) * 4 + 192;   // per-lane byte offset + s8q bias

    for (int i = 0; i < cntN; i += 8) {
        unsigned u0[8], u1[8];
        float    dv[8];
#pragma unroll
        for (int j = 0; j < 8; ++j) {
            uint2 e = lst[i + j];                      // ds_read_b64 broadcast
            u0[j] = (unsigned)__builtin_amdgcn_readfirstlane((int)e.x);
            u1[j] = (unsigned)__builtin_amdgcn_readfirstlane((int)e.y);
        }
#pragma unroll
        for (int j = 0; j < 8; ++j) {
            int t = (int)u0[j];                        // SGPR event id
            const char* dsb = (const char*)(ds + (size_t)t * 49);   // SGPR base
            int boc = min(max(vOff2 - (int)((u1[j] >> 16) & 511u), 0), 192);
            dv[j] = *(const float*)(dsb + boc);        // global_load v,off,s[base]
        }
        unsigned long long hmv[8], cmv[8];
#pragma unroll
        for (int j = 0; j < 8; ++j) {                  // s_load_dwordx2 from 2KB K$-hot table
            hmv[j] = mt[u1[j] & 255u];
            cmv[j] = mt[(u1[j] >> 8) & 255u];
        }
#pragma unroll
        for (int j = 0; j < 8; ++j) {
            float nim = fmaf(im, c, dv[j]) * __builtin_amdgcn_rcpf(c + 1.0f);
            asm("v_cndmask_b32 %0, %0, %1, %2" : "+v"(im) : "v"(nim), "s"(hmv[j]));
            float inc;
            asm("v_cndmask_b32 %0, 0, 1.0, %1" : "=v"(inc) : "s"(cmv[j]));
            c += inc;                                  // counter at transposed slice (source bug)
        }
    }
    out[bc * (HH * WW) + r * WW + cc] = im;
}

extern "C" void kernel_launch(void* const* d_in, const int* in_sizes, int n_in,
                              void* d_out, int out_size, void* d_ws, size_t ws_size,
                              hipStream_t stream) {
    const float* img = (const float*)d_in[0];
    const float* Wp  = (const float*)d_in[1];
    const float* bp  = (const float*)d_in[2];
    const float* pe  = (const float*)d_in[3];
    const float* Wb  = (const float*)d_in[4];
    const float* bb  = (const float*)d_in[5];
    float* out = (float*)d_out;

    float* wsf = (float*)d_ws;
    float*              M  = wsf;                               // 2401 floats (pad 2404)
    float*              K  = wsf + 2404;                        // 490 floats (pad 492)
    unsigned long long* MT = (unsigned long long*)(wsf + 2896); // 256 u64 = 512 floats
    unsigned*           xy = (unsigned*)(wsf + 3408);           // 414720 u32
    float*              pd = wsf + 3408 + NTASK;                // 20,321,280 floats

    k_mk<<<13, 256, 0, stream>>>(Wp, bp, pe, Wb, bb, M, K, MT);
    k_sim<<<BCN * PPOS / 4, 256, 0, stream>>>(img, M, K, xy, pd);
    k_apply<<<BCN * NTILE / 4, 256, 0, stream>>>(img, xy, pd, MT, out);
}